// Round 1
// baseline (727.374 us; speedup 1.0000x reference)
//
#include <hip/hip_runtime.h>

typedef __bf16 bf16;
typedef __bf16 bf16x4 __attribute__((ext_vector_type(4)));
typedef __bf16 bf16x8 __attribute__((ext_vector_type(8)));
typedef float f32x4 __attribute__((ext_vector_type(4)));

#define EMBED 1024
#define SEQ   2048
#define NH    16
#define DH    64
#define MROWS 4096   // B*S

__device__ __forceinline__ void gload16(const void* g, void* l) {
    __builtin_amdgcn_global_load_lds((const __attribute__((address_space(1))) void*)g,
                                     (__attribute__((address_space(3))) void*)l,
                                     16, 0, 0);
}

// ---------------- convert X (fp32 -> bf16) ----------------
__global__ void cvt_x_kernel(const float* __restrict__ x, bf16* __restrict__ xb) {
    int i = (blockIdx.x * 256 + threadIdx.x) * 4;
    float4 v = *(const float4*)(x + i);
    bf16x4 o;
    o[0] = (bf16)v.x; o[1] = (bf16)v.y; o[2] = (bf16)v.z; o[3] = (bf16)v.w;
    *(bf16x4*)(xb + i) = o;
}

// ------------- transpose + convert weights: Wb[n][k] = W[k][n] -------------
__global__ void cvt_wt_kernel(const float* __restrict__ w0, const float* __restrict__ w1,
                              const float* __restrict__ w2, const float* __restrict__ w3,
                              bf16* __restrict__ o0, bf16* __restrict__ o1,
                              bf16* __restrict__ o2, bf16* __restrict__ o3) {
    const float* w; bf16* o;
    switch (blockIdx.z) {
        case 0: w = w0; o = o0; break;
        case 1: w = w1; o = o1; break;
        case 2: w = w2; o = o2; break;
        default: w = w3; o = o3; break;
    }
    __shared__ float t[32][33];
    int tx = threadIdx.x & 31, ty = threadIdx.x >> 5;      // 32 x 8
    int c0 = blockIdx.x * 32, r0 = blockIdx.y * 32;
    #pragma unroll
    for (int i = 0; i < 32; i += 8)
        t[ty + i][tx] = w[(size_t)(r0 + ty + i) * EMBED + c0 + tx];
    __syncthreads();
    #pragma unroll
    for (int i = 0; i < 32; i += 8)
        o[(size_t)(c0 + ty + i) * EMBED + r0 + tx] = (bf16)t[tx][ty + i];
}

// ---------------- 128x128x64 bf16 MFMA GEMM body ----------------
// A: [M][1024] bf16 row-major; Bm: [N][1024] bf16 (i.e. W^T); C: [M][1024]
template <bool F32OUT>
__device__ __forceinline__ void gemm_body(const bf16* __restrict__ A,
                                          const bf16* __restrict__ Bm,
                                          const float* __restrict__ bias,
                                          void* __restrict__ Cout) {
    __shared__ bf16 As[128 * 64];
    __shared__ bf16 Bs[128 * 64];
    const int tid = threadIdx.x, wave = tid >> 6, lane = tid & 63;
    const int qd = lane >> 4, ln = lane & 15;
    const int m0 = blockIdx.y * 128, n0 = blockIdx.x * 128;
    const int wr = (wave >> 1) * 64, wc = (wave & 1) * 64;
    const int lrow8 = lane >> 3, lcol8 = (lane & 7) * 8;
    f32x4 acc[4][4] = {};

    for (int k0 = 0; k0 < EMBED; k0 += 64) {
        #pragma unroll
        for (int i = 0; i < 4; ++i) {
            int seg = i * 4 + wave;                       // 0..15, wave-uniform
            const bf16* ga = A  + (size_t)(m0 + seg * 8 + lrow8) * EMBED + k0 + lcol8;
            const bf16* gb = Bm + (size_t)(n0 + seg * 8 + lrow8) * EMBED + k0 + lcol8;
            gload16(ga, As + seg * 512);
            gload16(gb, Bs + seg * 512);
        }
        __syncthreads();
        #pragma unroll
        for (int kk = 0; kk < 64; kk += 32) {
            bf16x8 af[4], bfr[4];
            #pragma unroll
            for (int mt = 0; mt < 4; ++mt)
                af[mt] = *(const bf16x8*)(As + (wr + mt * 16 + ln) * 64 + kk + qd * 8);
            #pragma unroll
            for (int nt = 0; nt < 4; ++nt)
                bfr[nt] = *(const bf16x8*)(Bs + (wc + nt * 16 + ln) * 64 + kk + qd * 8);
            #pragma unroll
            for (int mt = 0; mt < 4; ++mt)
                #pragma unroll
                for (int nt = 0; nt < 4; ++nt)
                    acc[mt][nt] = __builtin_amdgcn_mfma_f32_16x16x32_bf16(
                        af[mt], bfr[nt], acc[mt][nt], 0, 0, 0);
        }
        __syncthreads();
    }
    #pragma unroll
    for (int mt = 0; mt < 4; ++mt) {
        #pragma unroll
        for (int nt = 0; nt < 4; ++nt) {
            int col = n0 + wc + nt * 16 + ln;
            float bv = bias[col];
            #pragma unroll
            for (int r = 0; r < 4; ++r) {
                int row = m0 + wr + mt * 16 + qd * 4 + r;
                float v = acc[mt][nt][r] + bv;
                if (F32OUT) ((float*)Cout)[(size_t)row * EMBED + col] = v;
                else        ((bf16*)Cout)[(size_t)row * EMBED + col] = (bf16)v;
            }
        }
    }
}

__global__ void gemm_qkv_kernel(const bf16* __restrict__ A,
                                const bf16* __restrict__ B0, const bf16* __restrict__ B1,
                                const bf16* __restrict__ B2,
                                const float* __restrict__ b0, const float* __restrict__ b1,
                                const float* __restrict__ b2,
                                bf16* __restrict__ C0, bf16* __restrict__ C1,
                                bf16* __restrict__ C2) {
    const bf16* Bm; const float* bias; bf16* C;
    switch (blockIdx.z) {
        case 0: Bm = B0; bias = b0; C = C0; break;
        case 1: Bm = B1; bias = b1; C = C1; break;
        default: Bm = B2; bias = b2; C = C2; break;
    }
    gemm_body<false>(A, Bm, bias, (void*)C);
}

__global__ void gemm_o_kernel(const bf16* __restrict__ A, const bf16* __restrict__ Bm,
                              const float* __restrict__ bias, float* __restrict__ C) {
    gemm_body<true>(A, Bm, bias, (void*)C);
}

// ---------------- fused attention ----------------
// grid: (16 q-blocks, 32 bh).  block: 256 threads (4 waves).
// Per block: Q rows qb*128..+128 of head (b,h).
// Pass 1: l[row] = sum_k exp(scale * q.k)   (QK^T MFMA, discard scores)
// Pass 2: recompute scores, P = exp*rl -> write fp32 weights to d_out,
//         bf16 P to LDS, O += P.V via MFMA (V transposed through LDS).
__global__ void attn_kernel(const bf16* __restrict__ Q, const bf16* __restrict__ K,
                            const bf16* __restrict__ V, float* __restrict__ Wout,
                            bf16* __restrict__ O) {
    const int qb = blockIdx.x;          // 0..15
    const int bh = blockIdx.y;          // 0..31  (b*16+h)
    const int b = bh >> 4, h = bh & 15;
    const size_t rowbase = (size_t)b * SEQ;
    const int colbase = h * DH;

    __shared__ bf16 Qs[128 * 64];       // 16 KB
    __shared__ bf16 Ks[64 * 64];        //  8 KB
    __shared__ bf16 Vts[64 * 72];       //  9 KB  Vts[d][kk], pad 72
    __shared__ bf16 Ps[128 * 72];       // 18 KB  Ps[row][kk], pad 72
    __shared__ float rl[128];

    const int tid = threadIdx.x, wave = tid >> 6, lane = tid & 63;
    const int qd = lane >> 4, ln = lane & 15;
    const int lrow8 = lane >> 3, lcol8 = (lane & 7) * 8;
    const float scale = 0.125f;

    // stage Q block once (completes at first barrier)
    #pragma unroll
    for (int i = 0; i < 4; ++i) {
        int seg = i * 4 + wave;
        gload16(Q + (rowbase + qb * 128 + seg * 8 + lrow8) * EMBED + colbase + lcol8,
                Qs + seg * 512);
    }

    float lsum[2][4] = {};

    // ---- pass 1 ----
    for (int kb = 0; kb < 32; ++kb) {
        #pragma unroll
        for (int i = 0; i < 2; ++i) {
            int seg = i * 4 + wave;     // 0..7
            gload16(K + (rowbase + kb * 64 + seg * 8 + lrow8) * EMBED + colbase + lcol8,
                    Ks + seg * 512);
        }
        __syncthreads();
        f32x4 sacc[2][4] = {};
        #pragma unroll
        for (int kk = 0; kk < 64; kk += 32) {
            bf16x8 af[2], bfr[4];
            #pragma unroll
            for (int mt = 0; mt < 2; ++mt)
                af[mt] = *(const bf16x8*)(Qs + (wave * 32 + mt * 16 + ln) * 64 + kk + qd * 8);
            #pragma unroll
            for (int nt = 0; nt < 4; ++nt)
                bfr[nt] = *(const bf16x8*)(Ks + (nt * 16 + ln) * 64 + kk + qd * 8);
            #pragma unroll
            for (int mt = 0; mt < 2; ++mt)
                #pragma unroll
                for (int nt = 0; nt < 4; ++nt)
                    sacc[mt][nt] = __builtin_amdgcn_mfma_f32_16x16x32_bf16(
                        af[mt], bfr[nt], sacc[mt][nt], 0, 0, 0);
        }
        #pragma unroll
        for (int mt = 0; mt < 2; ++mt)
            #pragma unroll
            for (int r = 0; r < 4; ++r) {
                float s = 0.f;
                #pragma unroll
                for (int nt = 0; nt < 4; ++nt) s += __expf(sacc[mt][nt][r] * scale);
                lsum[mt][r] += s;
            }
        __syncthreads();
    }
    // reduce across the 16 lanes of each quad (cols) -> 1/l
    #pragma unroll
    for (int mt = 0; mt < 2; ++mt)
        #pragma unroll
        for (int r = 0; r < 4; ++r) {
            float s = lsum[mt][r];
            s += __shfl_xor(s, 1); s += __shfl_xor(s, 2);
            s += __shfl_xor(s, 4); s += __shfl_xor(s, 8);
            if (ln == 0) rl[wave * 32 + mt * 16 + qd * 4 + r] = 1.0f / s;
        }

    // ---- pass 2 ----
    f32x4 oacc[2][4] = {};
    for (int kb = 0; kb < 32; ++kb) {
        #pragma unroll
        for (int i = 0; i < 2; ++i) {
            int seg = i * 4 + wave;
            gload16(K + (rowbase + kb * 64 + seg * 8 + lrow8) * EMBED + colbase + lcol8,
                    Ks + seg * 512);
        }
        {   // V tile -> LDS transposed
            int r = tid >> 2, dg = tid & 3;
            const bf16* vp = V + (rowbase + kb * 64 + r) * EMBED + colbase + dg * 16;
            bf16x8 v0 = *(const bf16x8*)(vp);
            bf16x8 v1 = *(const bf16x8*)(vp + 8);
            #pragma unroll
            for (int j = 0; j < 8; ++j) Vts[(dg * 16 + j) * 72 + r] = v0[j];
            #pragma unroll
            for (int j = 0; j < 8; ++j) Vts[(dg * 16 + 8 + j) * 72 + r] = v1[j];
        }
        __syncthreads();
        f32x4 sacc[2][4] = {};
        #pragma unroll
        for (int kk = 0; kk < 64; kk += 32) {
            bf16x8 af[2], bfr[4];
            #pragma unroll
            for (int mt = 0; mt < 2; ++mt)
                af[mt] = *(const bf16x8*)(Qs + (wave * 32 + mt * 16 + ln) * 64 + kk + qd * 8);
            #pragma unroll
            for (int nt = 0; nt < 4; ++nt)
                bfr[nt] = *(const bf16x8*)(Ks + (nt * 16 + ln) * 64 + kk + qd * 8);
            #pragma unroll
            for (int mt = 0; mt < 2; ++mt)
                #pragma unroll
                for (int nt = 0; nt < 4; ++nt)
                    sacc[mt][nt] = __builtin_amdgcn_mfma_f32_16x16x32_bf16(
                        af[mt], bfr[nt], sacc[mt][nt], 0, 0, 0);
        }
        // P = exp * rl : write global weights (fp32) + LDS bf16
        float* wb = Wout + ((size_t)bh * SEQ + qb * 128) * SEQ + kb * 64;
        #pragma unroll
        for (int mt = 0; mt < 2; ++mt) {
            int lrow = wave * 32 + mt * 16 + qd * 4;
            #pragma unroll
            for (int r = 0; r < 4; ++r) {
                float rli = rl[lrow + r];
                #pragma unroll
                for (int nt = 0; nt < 4; ++nt) {
                    float p = __expf(sacc[mt][nt][r] * scale) * rli;
                    wb[(size_t)(lrow + r) * SEQ + nt * 16 + ln] = p;
                    Ps[(lrow + r) * 72 + nt * 16 + ln] = (bf16)p;
                }
            }
        }
        // P.V  (own-wave Ps rows; lgkmcnt ordering within wave suffices)
        #pragma unroll
        for (int kk = 0; kk < 64; kk += 32) {
            bf16x8 pf[2], vf[4];
            #pragma unroll
            for (int mt = 0; mt < 2; ++mt)
                pf[mt] = *(const bf16x8*)(Ps + (wave * 32 + mt * 16 + ln) * 72 + kk + qd * 8);
            #pragma unroll
            for (int nt = 0; nt < 4; ++nt)
                vf[nt] = *(const bf16x8*)(Vts + (nt * 16 + ln) * 72 + kk + qd * 8);
            #pragma unroll
            for (int mt = 0; mt < 2; ++mt)
                #pragma unroll
                for (int nt = 0; nt < 4; ++nt)
                    oacc[mt][nt] = __builtin_amdgcn_mfma_f32_16x16x32_bf16(
                        pf[mt], vf[nt], oacc[mt][nt], 0, 0, 0);
        }
        __syncthreads();
    }
    // write O tile (bf16) [token][h*64+d]
    #pragma unroll
    for (int mt = 0; mt < 2; ++mt) {
        int lrow = wave * 32 + mt * 16 + qd * 4;
        #pragma unroll
        for (int nt = 0; nt < 4; ++nt) {
            int d = nt * 16 + ln;
            #pragma unroll
            for (int r = 0; r < 4; ++r)
                O[(rowbase + qb * 128 + lrow + r) * EMBED + colbase + d] = (bf16)oacc[mt][nt][r];
        }
    }
}

// ---------------- launch ----------------
extern "C" void kernel_launch(void* const* d_in, const int* in_sizes, int n_in,
                              void* d_out, int out_size, void* d_ws, size_t ws_size,
                              hipStream_t stream) {
    const float* x  = (const float*)d_in[0];
    const float* Wq = (const float*)d_in[1];
    const float* bq = (const float*)d_in[2];
    const float* Wk = (const float*)d_in[3];
    const float* bk = (const float*)d_in[4];
    const float* Wv = (const float*)d_in[5];
    const float* bv = (const float*)d_in[6];
    const float* Wo = (const float*)d_in[7];
    const float* bo = (const float*)d_in[8];

    float* out0 = (float*)d_out;                       // [2,2048,1024]
    float* Wout = (float*)d_out + (size_t)MROWS * EMBED; // weights [2,16,2048,2048]

    const size_t MB = 1u << 20;
    char* ws = (char*)d_ws;
    bf16* Xb  = (bf16*)(ws + 0 * MB);   // 8 MB
    bf16* Wqb = (bf16*)(ws + 8 * MB);   // 2 MB
    bf16* Wkb = (bf16*)(ws + 10 * MB);
    bf16* Wvb = (bf16*)(ws + 12 * MB);
    bf16* Wob = (bf16*)(ws + 14 * MB);
    bf16* Qb  = (bf16*)(ws + 16 * MB);  // 8 MB
    bf16* Kb  = (bf16*)(ws + 24 * MB);
    bf16* Vb  = (bf16*)(ws + 32 * MB);
    bf16* Ob  = (bf16*)(ws + 40 * MB);  // 8 MB  -> total 48 MB

    cvt_x_kernel<<<4096, 256, 0, stream>>>(x, Xb);
    cvt_wt_kernel<<<dim3(32, 32, 4), 256, 0, stream>>>(Wq, Wk, Wv, Wo, Wqb, Wkb, Wvb, Wob);
    gemm_qkv_kernel<<<dim3(8, 32, 3), 256, 0, stream>>>(Xb, Wqb, Wkb, Wvb, bq, bk, bv,
                                                        Qb, Kb, Vb);
    attn_kernel<<<dim3(16, 32), 256, 0, stream>>>(Qb, Kb, Vb, Wout, Ob);
    gemm_o_kernel<<<dim3(8, 32), 256, 0, stream>>>(Ob, Wob, bo, out0);
}